// Round 2
// 1241.835 us; speedup vs baseline: 1.1996x; 1.1996x over previous
//
#include <hip/hip_runtime.h>
#include <stdint.h>

typedef unsigned short u16;
typedef __attribute__((ext_vector_type(8))) short short8;
typedef __attribute__((ext_vector_type(4))) float floatx4;

#define T_DIM 1024
#define E_DIM 256
#define M_DIM 256
#define H_DIM 1024
#define V_DIM 32000
#define NROWS 2048   /* B*T */
#define GCHUNKS 32   /* cb-chunks in gate reduction stage 1 */

// ---- workspace layout (bytes) ----
#define OFS_LOCLOG   ((size_t)0)            // f32 [2048][32000]
#define OFS_W2T_LIN  ((size_t)262144000)    // bf16 [32000][1024]
#define OFS_W2T_LOC  ((size_t)327680000)    // bf16 [32000][1024]
#define OFS_W1T_LIN  ((size_t)393216000)    // bf16 [1024][512]
#define OFS_W1T_LOC  ((size_t)394264576)    // bf16 [1024][2048]
#define OFS_A1_LIN   ((size_t)398458880)    // bf16 [2048][512]  (states | x)
#define OFS_A1_LOC   ((size_t)400556032)    // bf16 [2048][2048] (x[t-0..t-7])
#define OFS_XBUF     ((size_t)408944640)    // f32 [2048][256]; later reused: gate tmp [2048][10][32]
#define OFS_DRIVE    ((size_t)411041792)    // f32 [2048][256]; tail of gate tmp spills here (free by then)
#define OFS_HLIN     ((size_t)413138944)    // bf16 [2048][1024]
#define OFS_HLOC     ((size_t)417333248)    // bf16 [2048][1024]
#define OFS_PSTATS   ((size_t)421527552)    // f32 [2 paths][5 stats][250 cb][2048 rows]
#define OFS_GATE     ((size_t)442007552)    // f32 [2048]

__device__ __forceinline__ u16 f2bf(float f) {
  unsigned u = __float_as_uint(f);
  return (u16)((u + 0x7fffu + ((u >> 16) & 1u)) >> 16);
}

__device__ __forceinline__ void async_copy16(const void* g, void* l) {
  __builtin_amdgcn_global_load_lds(
      (__attribute__((address_space(1))) void*)(void*)g,
      (__attribute__((address_space(3))) void*)l, 16, 0, 0);
}

// ---------- f32 [R][C] -> bf16 [C][R] transpose/convert ----------
__global__ void k_transpose(const float* __restrict__ src, u16* __restrict__ dst,
                            int R, int C) {
  __shared__ float tile[32][33];
  int c0 = blockIdx.x * 32, r0 = blockIdx.y * 32;
  int tx = threadIdx.x, ty = threadIdx.y;  // 32 x 8
  #pragma unroll
  for (int i = 0; i < 32; i += 8)
    tile[ty + i][tx] = src[(size_t)(r0 + ty + i) * C + (c0 + tx)];
  __syncthreads();
  #pragma unroll
  for (int i = 0; i < 32; i += 8)
    dst[(size_t)(c0 + ty + i) * R + (r0 + tx)] = f2bf(tile[tx][ty + i]);
}

// ---------- embedding gather: xbuf f32 + x-part of A1_lin (cols 256..511) ----------
__global__ void k_gather(const int* __restrict__ chars, const float* __restrict__ emb,
                         float* __restrict__ xbuf, u16* __restrict__ A1lin) {
  int row = blockIdx.x, e = threadIdx.x;
  int ch = chars[row];
  float v = emb[(size_t)ch * E_DIM + e];
  xbuf[(size_t)row * E_DIM + e] = v;
  A1lin[(size_t)row * 512 + 256 + e] = f2bf(v);
}

// ---------- local window stacking: A1_loc[row][o*256+e] = x[t-o][e] ----------
__global__ void k_locbuild(const float* __restrict__ xbuf, u16* __restrict__ A1loc) {
  int row = blockIdx.x, e = threadIdx.x;
  int t = row & (T_DIM - 1);
  #pragma unroll
  for (int o = 0; o < 8; o++) {
    float v = (t >= o) ? xbuf[(size_t)(row - o) * E_DIM + e] : 0.f;
    A1loc[(size_t)row * 2048 + o * E_DIM + e] = f2bf(v);
  }
}

// ---------- drive = x @ in_proj  (fp32, 8 rows per block) ----------
__global__ void k_drive(const float* __restrict__ xbuf, const float* __restrict__ in_proj,
                        float* __restrict__ drive) {
  __shared__ float xs[8 * 256];
  int m = threadIdx.x, r0 = blockIdx.x * 8;
  #pragma unroll
  for (int j = 0; j < 8; j++) xs[j * 256 + m] = xbuf[(size_t)(r0 + j) * 256 + m];
  __syncthreads();
  float acc[8] = {0.f, 0.f, 0.f, 0.f, 0.f, 0.f, 0.f, 0.f};
  for (int e = 0; e < 256; e++) {
    float w = in_proj[e * 256 + m];
    #pragma unroll
    for (int j = 0; j < 8; j++) acc[j] = fmaf(xs[j * 256 + e], w, acc[j]);
  }
  #pragma unroll
  for (int j = 0; j < 8; j++) drive[(size_t)(r0 + j) * 256 + m] = acc[j];
}

// ---------- decay scan: states -> A1_lin cols 0..255 (bf16) ----------
__global__ void k_scan(const float* __restrict__ drive, const float* __restrict__ decays,
                       u16* __restrict__ A1lin) {
  int m = threadIdx.x, b = blockIdx.x;
  float d = decays[m], s = 0.f;
  const float* dp = drive + (size_t)b * T_DIM * 256 + m;
  u16* op = A1lin + (size_t)b * T_DIM * 512 + m;
  for (int t = 0; t < T_DIM; t++) {
    s = fmaf(s, d, dp[(size_t)t * 256]);
    op[(size_t)t * 512] = f2bf(s);
  }
}

// ---------- bf16 MFMA GEMM: C[M][N] = A[M][K] @ Bt[N][K]^T + bias ----------
// MODE 0: relu, store bf16.  MODE 1: store f32 + per-(row,colblock) stat partials.
template <int MODE>
__global__ __launch_bounds__(256) void k_gemm(
    const u16* __restrict__ A, const u16* __restrict__ Bt,
    const float* __restrict__ bias, void* __restrict__ Cout,
    float* __restrict__ pstats, int M, int N, int K) {
  __shared__ u16 sA[128 * 64];
  __shared__ u16 sB[128 * 64];
  const int tid = threadIdx.x;
  const int lane = tid & 63;
  const int wv = tid >> 6;
  const int wrow = wv >> 1, wcol = wv & 1;
  const int lrow = lane & 15, quad = lane >> 4;
  const int m0 = blockIdx.y * 128, n0 = blockIdx.x * 128;

  floatx4 acc[4][4];
  #pragma unroll
  for (int i = 0; i < 4; i++)
    #pragma unroll
    for (int n = 0; n < 4; n++) acc[i][n] = (floatx4){0.f, 0.f, 0.f, 0.f};

  for (int k0 = 0; k0 < K; k0 += 64) {
    #pragma unroll
    for (int i = 0; i < 4; i++) {
      int c = i * 256 + tid;
      int row = c >> 3;
      int kc = (c & 7) ^ (row & 7);  // XOR swizzle: LDS chunk j holds global chunk j^(row&7)
      async_copy16(A + (size_t)(m0 + row) * K + k0 + kc * 8, (char*)sA + (size_t)c * 16);
    }
    #pragma unroll
    for (int i = 0; i < 4; i++) {
      int c = i * 256 + tid;
      int row = c >> 3;
      int kc = (c & 7) ^ (row & 7);
      async_copy16(Bt + (size_t)(n0 + row) * K + k0 + kc * 8, (char*)sB + (size_t)c * 16);
    }
    __syncthreads();
    #pragma unroll
    for (int s = 0; s < 2; s++) {
      short8 af[4], bfr[4];
      #pragma unroll
      for (int i = 0; i < 4; i++) {
        int ar = wrow * 64 + i * 16 + lrow;
        af[i] = *(const short8*)&sA[ar * 64 + ((s * 4 + quad) ^ (ar & 7)) * 8];
        int br = wcol * 64 + i * 16 + lrow;
        bfr[i] = *(const short8*)&sB[br * 64 + ((s * 4 + quad) ^ (br & 7)) * 8];
      }
      #pragma unroll
      for (int i = 0; i < 4; i++)
        #pragma unroll
        for (int n = 0; n < 4; n++)
          acc[i][n] = __builtin_amdgcn_mfma_f32_16x16x32_bf16(af[i], bfr[n], acc[i][n], 0, 0, 0);
    }
    __syncthreads();
  }

  if (MODE == 0) {
    u16* C = (u16*)Cout;
    #pragma unroll
    for (int i = 0; i < 4; i++) {
      int grow = m0 + wrow * 64 + i * 16 + quad * 4;
      #pragma unroll
      for (int n = 0; n < 4; n++) {
        int gcol = n0 + wcol * 64 + n * 16 + lrow;
        float bv = bias[gcol];
        #pragma unroll
        for (int r = 0; r < 4; r++) {
          float v = acc[i][n][r] + bv;
          v = v > 0.f ? v : 0.f;
          C[(size_t)(grow + r) * N + gcol] = f2bf(v);
        }
      }
    }
  } else {
    float* C = (float*)Cout;
    float* sStats = (float*)sA;  // 128*5*2 floats = 5120B, safe after trailing barrier
    #pragma unroll
    for (int i = 0; i < 4; i++) {
      #pragma unroll
      for (int r = 0; r < 4; r++) {
        int lr = wrow * 64 + i * 16 + quad * 4 + r;
        int grow = m0 + lr;
        float se = 0.f, sle = 0.f, sl = 0.f, sl2 = 0.f, mx = -1e30f;
        #pragma unroll
        for (int n = 0; n < 4; n++) {
          int gcol = n0 + wcol * 64 + n * 16 + lrow;
          float v = acc[i][n][r] + bias[gcol];
          C[(size_t)grow * N + gcol] = v;
          float e = __expf(v);
          se += e; sle += v * e; sl += v; sl2 += v * v; mx = fmaxf(mx, v);
        }
        #pragma unroll
        for (int off = 1; off < 16; off <<= 1) {
          se += __shfl_xor(se, off, 64);
          sle += __shfl_xor(sle, off, 64);
          sl += __shfl_xor(sl, off, 64);
          sl2 += __shfl_xor(sl2, off, 64);
          mx = fmaxf(mx, __shfl_xor(mx, off, 64));
        }
        if (lrow == 0) {
          float* p = &sStats[lr * 10 + wcol];
          p[0] = se; p[2] = sle; p[4] = sl; p[6] = sl2; p[8] = mx;
        }
      }
    }
    __syncthreads();
    if (tid < 128) {
      int lr = tid, grow = m0 + lr;
      #pragma unroll
      for (int s = 0; s < 5; s++) {
        float a = sStats[lr * 10 + s * 2 + 0], b = sStats[lr * 10 + s * 2 + 1];
        float v = (s == 4) ? fmaxf(a, b) : (a + b);
        pstats[((size_t)s * gridDim.x + blockIdx.x) * M + grow] = v;
      }
    }
  }
}

// ---------- gate stage 1: reduce 250 cb partials -> 32 chunk partials ----------
// grid (NROWS/256, GCHUNKS), 256 threads. Reads coalesced across rows.
// tmp layout: [row][10 segs][GCHUNKS], segs = {se,sle,sl,sl2}_p0, {se,sle,sl,sl2}_p1, mx_p0, mx_p1
__global__ void k_gstat1(const float* __restrict__ pstats, float* __restrict__ tmp) {
  int row = blockIdx.x * 256 + threadIdx.x;
  int ch = blockIdx.y;
  int cb0 = ch * 8;
  int cbn = cb0 + 8 < 250 ? cb0 + 8 : 250;   // chunk 31 covers cbs 248..249
  float* t = tmp + (size_t)row * (10 * GCHUNKS);
  #pragma unroll
  for (int p = 0; p < 2; p++) {
    const float* base = pstats + (size_t)p * 5 * 250 * NROWS;
    float se = 0.f, sle = 0.f, sl = 0.f, sl2 = 0.f, mx = -1e30f;
    for (int cb = cb0; cb < cbn; cb++) {
      se  += base[(size_t)(0 * 250 + cb) * NROWS + row];
      sle += base[(size_t)(1 * 250 + cb) * NROWS + row];
      sl  += base[(size_t)(2 * 250 + cb) * NROWS + row];
      sl2 += base[(size_t)(3 * 250 + cb) * NROWS + row];
      mx = fmaxf(mx, base[(size_t)(4 * 250 + cb) * NROWS + row]);
    }
    t[(p * 4 + 0) * GCHUNKS + ch] = se;
    t[(p * 4 + 1) * GCHUNKS + ch] = sle;
    t[(p * 4 + 2) * GCHUNKS + ch] = sl;
    t[(p * 4 + 3) * GCHUNKS + ch] = sl2;
    t[(8 + p) * GCHUNKS + ch] = mx;
  }
}

// ---------- gate stage 2: one wave per row; half-wave segmented reduction ----------
// Row's 320 partials are contiguous; value index vi = i*64+lane -> segment vi/32.
// Iters 0..3 hold sum-segments 0..7; iter 4 holds the two max-segments (8,9).
__global__ void k_gate2(const float* __restrict__ tmp, const float* __restrict__ gW,
                        const float* __restrict__ gb, float* __restrict__ gate) {
  int lane = threadIdx.x & 63, wv = threadIdx.x >> 6;
  int row = blockIdx.x * 4 + wv;
  const float* t = tmp + (size_t)row * (10 * GCHUNKS);
  float v[5];
  #pragma unroll
  for (int i = 0; i < 5; i++) v[i] = t[i * 64 + lane];
  #pragma unroll
  for (int i = 0; i < 4; i++) {
    #pragma unroll
    for (int off = 1; off < 32; off <<= 1) v[i] += __shfl_xor(v[i], off, 64);
  }
  #pragma unroll
  for (int off = 1; off < 32; off <<= 1) v[4] = fmaxf(v[4], __shfl_xor(v[4], off, 64));
  float seg[10];
  #pragma unroll
  for (int i = 0; i < 5; i++) {
    seg[2 * i]     = __shfl(v[i], 0, 64);
    seg[2 * i + 1] = __shfl(v[i], 32, 64);
  }
  if (lane == 0) {
    float f[6];
    #pragma unroll
    for (int p = 0; p < 2; p++) {
      float se = seg[p * 4 + 0], sle = seg[p * 4 + 1];
      float sl = seg[p * 4 + 2], sl2 = seg[p * 4 + 3], mx = seg[8 + p];
      float ent = logf(se) - sle / se;           // logits tiny, no shift needed
      float mean = sl * (1.f / V_DIM);
      float var = sl2 * (1.f / V_DIM) - mean * mean;
      f[p * 3 + 0] = ent; f[p * 3 + 1] = mx; f[p * 3 + 2] = var;
    }
    float z = gb[0];
    #pragma unroll
    for (int j = 0; j < 6; j++) z = fmaf(f[j], gW[j], z);
    gate[row] = 1.f / (1.f + __expf(-z));
  }
}

// ---------- mix: out = g*lin + (1-g)*loc  (lin is in d_out, in-place) ----------
__global__ void k_mix(float* __restrict__ out, const float* __restrict__ loc,
                      const float* __restrict__ gate) {
  const unsigned total = (unsigned)NROWS * (V_DIM / 4);  // 16,384,000 float4s
  unsigned stride = gridDim.x * blockDim.x;
  for (unsigned q = blockIdx.x * blockDim.x + threadIdx.x; q < total; q += stride) {
    unsigned row = q / (V_DIM / 4);
    float g = gate[row], h = 1.f - g;
    float4 a = ((const float4*)out)[q];
    float4 b = ((const float4*)loc)[q];
    float4 o;
    o.x = g * a.x + h * b.x;
    o.y = g * a.y + h * b.y;
    o.z = g * a.z + h * b.z;
    o.w = g * a.w + h * b.w;
    ((float4*)out)[q] = o;
  }
}

extern "C" void kernel_launch(void* const* d_in, const int* in_sizes, int n_in,
                              void* d_out, int out_size, void* d_ws, size_t ws_size,
                              hipStream_t stream) {
  const int*   chars   = (const int*)d_in[0];
  const float* emb     = (const float*)d_in[1];
  const float* in_proj = (const float*)d_in[2];
  const float* decays  = (const float*)d_in[3];
  const float* lin_W1  = (const float*)d_in[4];
  const float* lin_b1  = (const float*)d_in[5];
  const float* lin_W2  = (const float*)d_in[6];
  const float* lin_b2  = (const float*)d_in[7];
  const float* loc_W1  = (const float*)d_in[8];
  const float* loc_b1  = (const float*)d_in[9];
  const float* loc_W2  = (const float*)d_in[10];
  const float* loc_b2  = (const float*)d_in[11];
  const float* gate_W  = (const float*)d_in[12];
  const float* gate_b  = (const float*)d_in[13];

  char* ws = (char*)d_ws;
  float* loc_logits = (float*)(ws + OFS_LOCLOG);
  u16* W2t_lin = (u16*)(ws + OFS_W2T_LIN);
  u16* W2t_loc = (u16*)(ws + OFS_W2T_LOC);
  u16* W1t_lin = (u16*)(ws + OFS_W1T_LIN);
  u16* W1t_loc = (u16*)(ws + OFS_W1T_LOC);
  u16* A1_lin  = (u16*)(ws + OFS_A1_LIN);
  u16* A1_loc  = (u16*)(ws + OFS_A1_LOC);
  float* xbuf  = (float*)(ws + OFS_XBUF);
  float* drive = (float*)(ws + OFS_DRIVE);
  u16* h_lin   = (u16*)(ws + OFS_HLIN);
  u16* h_loc   = (u16*)(ws + OFS_HLOC);
  float* pstats = (float*)(ws + OFS_PSTATS);
  float* gate  = (float*)(ws + OFS_GATE);
  float* gtmp  = (float*)(ws + OFS_XBUF);  // 2048*10*32*4 = 2.62 MB; xbuf+drive (4 MB) free by gate time
  float* out   = (float*)d_out;

  dim3 tb(32, 8);
  // weight transpose+convert: [in][out] f32 -> [out][in] bf16
  k_transpose<<<dim3(H_DIM / 32, 512 / 32), tb, 0, stream>>>(lin_W1, W1t_lin, 512, H_DIM);
  k_transpose<<<dim3(H_DIM / 32, 2048 / 32), tb, 0, stream>>>(loc_W1, W1t_loc, 2048, H_DIM);
  k_transpose<<<dim3(V_DIM / 32, H_DIM / 32), tb, 0, stream>>>(lin_W2, W2t_lin, H_DIM, V_DIM);
  k_transpose<<<dim3(V_DIM / 32, H_DIM / 32), tb, 0, stream>>>(loc_W2, W2t_loc, H_DIM, V_DIM);

  k_gather<<<NROWS, 256, 0, stream>>>(chars, emb, xbuf, A1_lin);
  k_locbuild<<<NROWS, 256, 0, stream>>>(xbuf, A1_loc);
  k_drive<<<NROWS / 8, 256, 0, stream>>>(xbuf, in_proj, drive);
  k_scan<<<2, 256, 0, stream>>>(drive, decays, A1_lin);

  // hidden layers (relu, bf16 out)
  k_gemm<0><<<dim3(H_DIM / 128, NROWS / 128), 256, 0, stream>>>(
      A1_lin, W1t_lin, lin_b1, (void*)h_lin, nullptr, NROWS, H_DIM, 512);
  k_gemm<0><<<dim3(H_DIM / 128, NROWS / 128), 256, 0, stream>>>(
      A1_loc, W1t_loc, loc_b1, (void*)h_loc, nullptr, NROWS, H_DIM, 2048);

  // output layers (f32 logits + stats partials); lin logits go straight to d_out
  k_gemm<1><<<dim3(V_DIM / 128, NROWS / 128), 256, 0, stream>>>(
      h_lin, W2t_lin, lin_b2, (void*)out, pstats, NROWS, V_DIM, H_DIM);
  k_gemm<1><<<dim3(V_DIM / 128, NROWS / 128), 256, 0, stream>>>(
      h_loc, W2t_loc, loc_b2, (void*)loc_logits, pstats + (size_t)5 * 250 * NROWS,
      NROWS, V_DIM, H_DIM);

  // gate: two-stage parallel reduction (was: 8-block serial k_gate at ~267 µs)
  k_gstat1<<<dim3(NROWS / 256, GCHUNKS), 256, 0, stream>>>(pstats, gtmp);
  k_gate2<<<NROWS / 4, 256, 0, stream>>>(gtmp, gate_W, gate_b, gate);

  k_mix<<<8192, 256, 0, stream>>>(out, loc_logits, gate);
}